// Round 1
// baseline (395.856 us; speedup 1.0000x reference)
//
#include <hip/hip_runtime.h>
#include <math.h>

#define QMAX 127.0f
#define CIN 32
#define CR 8
#define HW 16384                 // 128*128
#define BATCH 64
#define NPIX (BATCH*HW)          // 1,048,576 pixels
#define NQUAD (NPIX/4)           // 262,144 threads, 1024 blocks x 256
#define NX (BATCH*CIN*HW)        // 33,554,432 x elements

// ws layout (floats): [0]=amax_x bits, [1]=amax_h bits (as uint), [8..264)=wq_reduce, [264..520)=wq_expand

__device__ __forceinline__ float fq(float v, float inv_scale, float scale) {
    // round(clip(v/scale, -127, 127)) * scale ; rintf == round-half-even (v_rndne_f32)
    return rintf(fminf(fmaxf(v * inv_scale, -QMAX), QMAX)) * scale;
}
__device__ __forceinline__ float sigmoidf_(float v) {
    return 1.0f / (1.0f + __expf(-v));
}

// ---- K0: quantize weights into ws, zero amax accumulators ----
__global__ __launch_bounds__(256) void k0_prep(const float* __restrict__ wr,
                                               const float* __restrict__ we,
                                               float* __restrict__ wsf,
                                               unsigned int* __restrict__ wsu) {
    int t = threadIdx.x;
    if (t < 2) wsu[t] = 0u;
    __shared__ float amr[CR], ame[CIN];
    if (t < CR) {
        float m = 0.f;
        for (int c = 0; c < CIN; c++) m = fmaxf(m, fabsf(wr[t * CIN + c]));
        amr[t] = fmaxf(m, 1e-12f);
    }
    if (t >= 64 && t < 64 + CIN) {          // second wave: expand-weight row amax
        int r = t - 64;
        float m = 0.f;
        for (int c = 0; c < CR; c++) m = fmaxf(m, fabsf(we[r * CR + c]));
        ame[r] = fmaxf(m, 1e-12f);
    }
    __syncthreads();
    {   // w_reduce: 8 rows x 32, element t
        int r = t >> 5;
        float amax = amr[r];
        wsf[8 + t] = fq(wr[t], QMAX / amax, amax * (1.f / QMAX));
    }
    {   // w_expand: 32 rows x 8, element t
        int r = t >> 3;
        float amax = ame[r];
        wsf[264 + t] = fq(we[t], QMAX / amax, amax * (1.f / QMAX));
    }
}

// ---- K1: global max|x| ----
__global__ __launch_bounds__(256) void k1_xmax(const float4* __restrict__ x4,
                                               unsigned int* __restrict__ wsu) {
    float m = 0.f;
    int stride = gridDim.x * 256;
    for (int i = blockIdx.x * 256 + threadIdx.x; i < NX / 4; i += stride) {
        float4 v = x4[i];
        m = fmaxf(m, fmaxf(fmaxf(fabsf(v.x), fabsf(v.y)), fmaxf(fabsf(v.z), fabsf(v.w))));
    }
#pragma unroll
    for (int off = 32; off > 0; off >>= 1) m = fmaxf(m, __shfl_xor(m, off, 64));
    __shared__ float red[4];
    int t = threadIdx.x;
    if ((t & 63) == 0) red[t >> 6] = m;
    __syncthreads();
    if (t == 0) {
        m = fmaxf(fmaxf(red[0], red[1]), fmaxf(red[2], red[3]));
        atomicMax(&wsu[0], __float_as_uint(m));   // non-negative floats: uint order == float order
    }
}

// ---- K2: h = SiLU(conv_reduce(quant(x))) ; global max|h| ----
__global__ __launch_bounds__(256) void k2_hmax(const float* __restrict__ x,
                                               const float* __restrict__ br,
                                               const float* __restrict__ wsf,
                                               const unsigned int* __restrict__ wsu,
                                               unsigned int* __restrict__ hmax) {
    __shared__ float wq[CR * CIN];
    __shared__ float bsh[CR];
    int t = threadIdx.x;
    wq[t] = wsf[8 + t];
    if (t < CR) bsh[t] = br[t];
    __syncthreads();
    float a_amax = fmaxf(__uint_as_float(wsu[0]), 1e-12f);
    float scale = a_amax * (1.f / QMAX), inv_scale = QMAX / a_amax;
    int tid = blockIdx.x * 256 + t;
    int b = tid >> 12;                  // 4096 quads per image
    int hw = (tid & 4095) << 2;
    const float* xb = x + (size_t)b * CIN * HW + hw;
    float hacc[CR][4];
#pragma unroll
    for (int o = 0; o < CR; o++)
#pragma unroll
        for (int v = 0; v < 4; v++) hacc[o][v] = 0.f;
#pragma unroll
    for (int c = 0; c < CIN; c++) {
        float4 xv = *(const float4*)(xb + (size_t)c * HW);
        float q0 = fq(xv.x, inv_scale, scale), q1 = fq(xv.y, inv_scale, scale);
        float q2 = fq(xv.z, inv_scale, scale), q3 = fq(xv.w, inv_scale, scale);
#pragma unroll
        for (int o = 0; o < CR; o++) {
            float w = wq[o * CIN + c];
            hacc[o][0] += q0 * w; hacc[o][1] += q1 * w;
            hacc[o][2] += q2 * w; hacc[o][3] += q3 * w;
        }
    }
    float m = 0.f;
#pragma unroll
    for (int o = 0; o < CR; o++) {
        float bb = bsh[o];
#pragma unroll
        for (int v = 0; v < 4; v++) {
            float h = hacc[o][v] + bb;
            h = h * sigmoidf_(h);
            m = fmaxf(m, fabsf(h));
        }
    }
#pragma unroll
    for (int off = 32; off > 0; off >>= 1) m = fmaxf(m, __shfl_xor(m, off, 64));
    __shared__ float red[4];
    if ((t & 63) == 0) red[t >> 6] = m;
    __syncthreads();
    if (t == 0) {
        m = fmaxf(fmaxf(red[0], red[1]), fmaxf(red[2], red[3]));
        atomicMax(hmax, __float_as_uint(m));
    }
}

// ---- K3: recompute h (bit-identical), quantize, expand conv, identity * sigmoid(g) ----
__global__ __launch_bounds__(256) void k3_out(const float* __restrict__ x,
                                              const float* __restrict__ identity,
                                              const float* __restrict__ br,
                                              const float* __restrict__ be,
                                              const float* __restrict__ wsf,
                                              const unsigned int* __restrict__ wsu,
                                              float* __restrict__ out) {
    __shared__ float wqr[CR * CIN], wqe[CIN * CR], bsh[CR], besh[CIN];
    int t = threadIdx.x;
    wqr[t] = wsf[8 + t];
    wqe[t] = wsf[264 + t];
    if (t < CR) bsh[t] = br[t];
    if (t < CIN) besh[t] = be[t];
    __syncthreads();
    float a_amax = fmaxf(__uint_as_float(wsu[0]), 1e-12f);
    float ascale = a_amax * (1.f / QMAX), ainv = QMAX / a_amax;
    float h_amax = fmaxf(__uint_as_float(wsu[1]), 1e-12f);
    float hscale = h_amax * (1.f / QMAX), hinv = QMAX / h_amax;
    int tid = blockIdx.x * 256 + t;
    int b = tid >> 12;
    int hw = (tid & 4095) << 2;
    size_t base = (size_t)b * CIN * HW + hw;
    const float* xb = x + base;

    float hq[CR][4];
    {
        float hacc[CR][4];
#pragma unroll
        for (int o = 0; o < CR; o++)
#pragma unroll
            for (int v = 0; v < 4; v++) hacc[o][v] = 0.f;
#pragma unroll
        for (int c = 0; c < CIN; c++) {
            float4 xv = *(const float4*)(xb + (size_t)c * HW);
            float q0 = fq(xv.x, ainv, ascale), q1 = fq(xv.y, ainv, ascale);
            float q2 = fq(xv.z, ainv, ascale), q3 = fq(xv.w, ainv, ascale);
#pragma unroll
            for (int o = 0; o < CR; o++) {
                float w = wqr[o * CIN + c];
                hacc[o][0] += q0 * w; hacc[o][1] += q1 * w;
                hacc[o][2] += q2 * w; hacc[o][3] += q3 * w;
            }
        }
#pragma unroll
        for (int o = 0; o < CR; o++) {
            float bb = bsh[o];
#pragma unroll
            for (int v = 0; v < 4; v++) {
                float h = hacc[o][v] + bb;
                h = h * sigmoidf_(h);          // same op order as k2 -> identical fp result
                hq[o][v] = fq(h, hinv, hscale);
            }
        }
    }
#pragma unroll 4
    for (int o2 = 0; o2 < CIN; o2++) {
        float g0 = besh[o2], g1 = g0, g2 = g0, g3 = g0;
#pragma unroll
        for (int cr = 0; cr < CR; cr++) {
            float w = wqe[o2 * CR + cr];
            g0 += hq[cr][0] * w; g1 += hq[cr][1] * w;
            g2 += hq[cr][2] * w; g3 += hq[cr][3] * w;
        }
        float4 idv = *(const float4*)(identity + base + (size_t)o2 * HW);
        float4 ov;
        ov.x = idv.x * sigmoidf_(g0);
        ov.y = idv.y * sigmoidf_(g1);
        ov.z = idv.z * sigmoidf_(g2);
        ov.w = idv.w * sigmoidf_(g3);
        *(float4*)(out + base + (size_t)o2 * HW) = ov;
    }
}

extern "C" void kernel_launch(void* const* d_in, const int* in_sizes, int n_in,
                              void* d_out, int out_size, void* d_ws, size_t ws_size,
                              hipStream_t stream) {
    const float* x        = (const float*)d_in[0];
    const float* identity = (const float*)d_in[1];
    const float* wr       = (const float*)d_in[2];
    const float* br       = (const float*)d_in[3];
    const float* we       = (const float*)d_in[4];
    const float* be       = (const float*)d_in[5];
    float* out            = (float*)d_out;
    float* wsf            = (float*)d_ws;
    unsigned int* wsu     = (unsigned int*)d_ws;

    hipLaunchKernelGGL(k0_prep, dim3(1), dim3(256), 0, stream, wr, we, wsf, wsu);
    hipLaunchKernelGGL(k1_xmax, dim3(2048), dim3(256), 0, stream, (const float4*)x, wsu);
    hipLaunchKernelGGL(k2_hmax, dim3(NQUAD / 256), dim3(256), 0, stream, x, br, wsf, wsu, &wsu[1]);
    hipLaunchKernelGGL(k3_out,  dim3(NQUAD / 256), dim3(256), 0, stream, x, identity, br, be, wsf, wsu, out);
}

// Round 2
// 382.943 us; speedup vs baseline: 1.0337x; 1.0337x over previous
//
#include <hip/hip_runtime.h>
#include <math.h>

#define QMAX 127.0f
#define CIN 32
#define CR 8
#define HW 16384                 // 128*128
#define BATCH 64
#define NPIX (BATCH*HW)          // 1,048,576 pixels
#define NQUAD (NPIX/4)           // 262,144 pixel-quads
#define NX (BATCH*CIN*HW)        // 33,554,432 x elements

// ws layout: wsu[0]=amax_x bits, wsu[1]=amax_h bits; h buffer at wsf+64 (NPIX*CR floats = 32 MB)
#define H_OFF 64
#define WS_NEEDED ((size_t)(H_OFF + (size_t)NPIX * CR) * 4)

__device__ __forceinline__ float fq(float v, float inv_scale, float scale) {
    return rintf(fminf(fmaxf(v * inv_scale, -QMAX), QMAX)) * scale;  // round-half-even
}
__device__ __forceinline__ float sigmoidf_(float v) {
    return 1.0f / (1.0f + __expf(-v));
}

// ---- K1: global max|x|, 16 outstanding float4 loads/thread ----
__global__ __launch_bounds__(256) void k1_xmax(const float4* __restrict__ x4,
                                               unsigned int* __restrict__ wsu) {
    int idx = blockIdx.x * 256 + threadIdx.x;   // grid 2048 -> 524288 threads, 16 iters
    float m = 0.f;
#pragma unroll
    for (int i = 0; i < 16; i++) {
        float4 v = x4[idx + i * 524288];
        m = fmaxf(m, fmaxf(fmaxf(fabsf(v.x), fabsf(v.y)), fmaxf(fabsf(v.z), fabsf(v.w))));
    }
#pragma unroll
    for (int off = 32; off > 0; off >>= 1) m = fmaxf(m, __shfl_xor(m, off, 64));
    __shared__ float red[4];
    int t = threadIdx.x;
    if ((t & 63) == 0) red[t >> 6] = m;
    __syncthreads();
    if (t == 0) {
        m = fmaxf(fmaxf(red[0], red[1]), fmaxf(red[2], red[3]));
        atomicMax(&wsu[0], __float_as_uint(m));   // x>=0 after fabs: uint order == float order
    }
}

// ---- K2: h = SiLU(conv_reduce(quant(x))); optional h store; global max|h| ----
__global__ __launch_bounds__(256) void k2_hmax(const float* __restrict__ x,
                                               const float* __restrict__ wr,
                                               const float* __restrict__ br,
                                               const unsigned int* __restrict__ wsu,
                                               unsigned int* __restrict__ hmax,
                                               float* __restrict__ hbuf) {
    __shared__ float wq[CR * CIN], bsh[CR], amr[CR];
    int t = threadIdx.x;
    if (t < CR) {
        float mm = 0.f;
        for (int c = 0; c < CIN; c++) mm = fmaxf(mm, fabsf(wr[t * CIN + c]));
        amr[t] = fmaxf(mm, 1e-12f);
        bsh[t] = br[t];
    }
    __syncthreads();
    {
        float amax = amr[t >> 5];
        wq[t] = fq(wr[t], QMAX / amax, amax * (1.f / QMAX));
    }
    __syncthreads();
    float a_amax = fmaxf(__uint_as_float(wsu[0]), 1e-12f);
    float scale = a_amax * (1.f / QMAX), inv_scale = QMAX / a_amax;
    int tid = blockIdx.x * 256 + t;
    int b = tid >> 12;                  // 4096 quads per image
    int hw = (tid & 4095) << 2;
    const float* xb = x + (size_t)b * CIN * HW + hw;
    float hacc[CR][4];
#pragma unroll
    for (int o = 0; o < CR; o++)
#pragma unroll
        for (int v = 0; v < 4; v++) hacc[o][v] = 0.f;
#pragma unroll
    for (int c = 0; c < CIN; c++) {
        float4 xv = *(const float4*)(xb + (size_t)c * HW);
        float q0 = fq(xv.x, inv_scale, scale), q1 = fq(xv.y, inv_scale, scale);
        float q2 = fq(xv.z, inv_scale, scale), q3 = fq(xv.w, inv_scale, scale);
#pragma unroll
        for (int o = 0; o < CR; o++) {
            float w = wq[o * CIN + c];
            hacc[o][0] += q0 * w; hacc[o][1] += q1 * w;
            hacc[o][2] += q2 * w; hacc[o][3] += q3 * w;
        }
    }
    float m = 0.f;
#pragma unroll
    for (int o = 0; o < CR; o++) {
        float bb = bsh[o];
        float4 hv;
        float* hp = (float*)&hv;
#pragma unroll
        for (int v = 0; v < 4; v++) {
            float h = hacc[o][v] + bb;
            h = h * sigmoidf_(h);
            hp[v] = h;
            m = fmaxf(m, fabsf(h));
        }
        if (hbuf) *(float4*)(hbuf + ((size_t)(b * CR + o)) * HW + hw) = hv;
    }
#pragma unroll
    for (int off = 32; off > 0; off >>= 1) m = fmaxf(m, __shfl_xor(m, off, 64));
    __shared__ float red[4];
    if ((t & 63) == 0) red[t >> 6] = m;
    __syncthreads();
    if (t == 0) {
        m = fmaxf(fmaxf(red[0], red[1]), fmaxf(red[2], red[3]));
        atomicMax(hmax, __float_as_uint(m));
    }
}

// ---- K3 (fast): read h from ws, quantize, expand conv (16 out-ch per block via blockIdx.y) ----
__global__ __launch_bounds__(256) void k3_out(const float* __restrict__ hbuf,
                                              const float* __restrict__ identity,
                                              const float* __restrict__ we,
                                              const float* __restrict__ be,
                                              const unsigned int* __restrict__ wsu,
                                              float* __restrict__ out) {
    const int y = blockIdx.y;                 // 0/1: output channels [16y, 16y+16)
    __shared__ float wqe[16 * CR], besh[16], ame[16];
    int t = threadIdx.x;
    if (t < 16) {
        int r = 16 * y + t;
        float mm = 0.f;
        for (int c = 0; c < CR; c++) mm = fmaxf(mm, fabsf(we[r * CR + c]));
        ame[t] = fmaxf(mm, 1e-12f);
        besh[t] = be[r];
    }
    __syncthreads();
    if (t < 128) {
        int r16 = t >> 3;
        float amax = ame[r16];
        wqe[t] = fq(we[(16 * y + r16) * CR + (t & 7)], QMAX / amax, amax * (1.f / QMAX));
    }
    __syncthreads();
    float h_amax = fmaxf(__uint_as_float(wsu[1]), 1e-12f);
    float hscale = h_amax * (1.f / QMAX), hinv = QMAX / h_amax;
    int tid = blockIdx.x * 256 + t;
    int b = tid >> 12;
    int hw = (tid & 4095) << 2;
    size_t base = (size_t)b * CIN * HW + hw;

    float hq[CR][4];
#pragma unroll
    for (int cr = 0; cr < CR; cr++) {
        float4 hv = *(const float4*)(hbuf + ((size_t)(b * CR + cr)) * HW + hw);
        hq[cr][0] = fq(hv.x, hinv, hscale);
        hq[cr][1] = fq(hv.y, hinv, hscale);
        hq[cr][2] = fq(hv.z, hinv, hscale);
        hq[cr][3] = fq(hv.w, hinv, hscale);
    }
#pragma unroll 4
    for (int o = 0; o < 16; o++) {
        float g0 = besh[o], g1 = g0, g2 = g0, g3 = g0;
#pragma unroll
        for (int cr = 0; cr < CR; cr++) {
            float w = wqe[o * CR + cr];
            g0 += hq[cr][0] * w; g1 += hq[cr][1] * w;
            g2 += hq[cr][2] * w; g3 += hq[cr][3] * w;
        }
        size_t off = base + (size_t)(16 * y + o) * HW;
        float4 idv = *(const float4*)(identity + off);
        float4 ov;
        ov.x = idv.x * sigmoidf_(g0);
        ov.y = idv.y * sigmoidf_(g1);
        ov.z = idv.z * sigmoidf_(g2);
        ov.w = idv.w * sigmoidf_(g3);
        *(float4*)(out + off) = ov;
    }
}

// ---- K3 (fallback, ws too small): recompute h from x (bit-identical to k2) ----
__global__ __launch_bounds__(256) void k3_out_rc(const float* __restrict__ x,
                                                 const float* __restrict__ identity,
                                                 const float* __restrict__ wr,
                                                 const float* __restrict__ br,
                                                 const float* __restrict__ we,
                                                 const float* __restrict__ be,
                                                 const unsigned int* __restrict__ wsu,
                                                 float* __restrict__ out) {
    __shared__ float wqr[CR * CIN], wqe[CIN * CR], bsh[CR], besh[CIN], amr[CR], ame[CIN];
    int t = threadIdx.x;
    if (t < CR) {
        float mm = 0.f;
        for (int c = 0; c < CIN; c++) mm = fmaxf(mm, fabsf(wr[t * CIN + c]));
        amr[t] = fmaxf(mm, 1e-12f);
        bsh[t] = br[t];
    }
    if (t >= 64 && t < 64 + CIN) {
        int r = t - 64;
        float mm = 0.f;
        for (int c = 0; c < CR; c++) mm = fmaxf(mm, fabsf(we[r * CR + c]));
        ame[r] = fmaxf(mm, 1e-12f);
        besh[r] = be[r];
    }
    __syncthreads();
    {
        float amax = amr[t >> 5];
        wqr[t] = fq(wr[t], QMAX / amax, amax * (1.f / QMAX));
        float amax2 = ame[t >> 3];
        wqe[t] = fq(we[t], QMAX / amax2, amax2 * (1.f / QMAX));
    }
    __syncthreads();
    float a_amax = fmaxf(__uint_as_float(wsu[0]), 1e-12f);
    float ascale = a_amax * (1.f / QMAX), ainv = QMAX / a_amax;
    float h_amax = fmaxf(__uint_as_float(wsu[1]), 1e-12f);
    float hscale = h_amax * (1.f / QMAX), hinv = QMAX / h_amax;
    int tid = blockIdx.x * 256 + t;
    int b = tid >> 12;
    int hw = (tid & 4095) << 2;
    size_t base = (size_t)b * CIN * HW + hw;
    const float* xb = x + base;
    float hq[CR][4];
    {
        float hacc[CR][4];
#pragma unroll
        for (int o = 0; o < CR; o++)
#pragma unroll
            for (int v = 0; v < 4; v++) hacc[o][v] = 0.f;
#pragma unroll
        for (int c = 0; c < CIN; c++) {
            float4 xv = *(const float4*)(xb + (size_t)c * HW);
            float q0 = fq(xv.x, ainv, ascale), q1 = fq(xv.y, ainv, ascale);
            float q2 = fq(xv.z, ainv, ascale), q3 = fq(xv.w, ainv, ascale);
#pragma unroll
            for (int o = 0; o < CR; o++) {
                float w = wqr[o * CIN + c];
                hacc[o][0] += q0 * w; hacc[o][1] += q1 * w;
                hacc[o][2] += q2 * w; hacc[o][3] += q3 * w;
            }
        }
#pragma unroll
        for (int o = 0; o < CR; o++) {
            float bb = bsh[o];
#pragma unroll
            for (int v = 0; v < 4; v++) {
                float h = hacc[o][v] + bb;
                h = h * sigmoidf_(h);
                hq[o][v] = fq(h, hinv, hscale);
            }
        }
    }
#pragma unroll 4
    for (int o2 = 0; o2 < CIN; o2++) {
        float g0 = besh[o2], g1 = g0, g2 = g0, g3 = g0;
#pragma unroll
        for (int cr = 0; cr < CR; cr++) {
            float w = wqe[o2 * CR + cr];
            g0 += hq[cr][0] * w; g1 += hq[cr][1] * w;
            g2 += hq[cr][2] * w; g3 += hq[cr][3] * w;
        }
        size_t off = base + (size_t)o2 * HW;
        float4 idv = *(const float4*)(identity + off);
        float4 ov;
        ov.x = idv.x * sigmoidf_(g0);
        ov.y = idv.y * sigmoidf_(g1);
        ov.z = idv.z * sigmoidf_(g2);
        ov.w = idv.w * sigmoidf_(g3);
        *(float4*)(out + off) = ov;
    }
}

extern "C" void kernel_launch(void* const* d_in, const int* in_sizes, int n_in,
                              void* d_out, int out_size, void* d_ws, size_t ws_size,
                              hipStream_t stream) {
    const float* x        = (const float*)d_in[0];
    const float* identity = (const float*)d_in[1];
    const float* wr       = (const float*)d_in[2];
    const float* br       = (const float*)d_in[3];
    const float* we       = (const float*)d_in[4];
    const float* be       = (const float*)d_in[5];
    float* out            = (float*)d_out;
    float* wsf            = (float*)d_ws;
    unsigned int* wsu     = (unsigned int*)d_ws;
    const bool big_ws     = (ws_size >= WS_NEEDED);
    float* hbuf           = big_ws ? (wsf + H_OFF) : nullptr;

    hipMemsetAsync(d_ws, 0, 16, stream);   // zero amax accumulators (ws re-poisoned to 0xAA)
    hipLaunchKernelGGL(k1_xmax, dim3(2048), dim3(256), 0, stream, (const float4*)x, wsu);
    hipLaunchKernelGGL(k2_hmax, dim3(NQUAD / 256), dim3(256), 0, stream,
                       x, wr, br, wsu, &wsu[1], hbuf);
    if (big_ws) {
        hipLaunchKernelGGL(k3_out, dim3(NQUAD / 256, 2), dim3(256), 0, stream,
                           hbuf, identity, we, be, wsu, out);
    } else {
        hipLaunchKernelGGL(k3_out_rc, dim3(NQUAD / 256), dim3(256), 0, stream,
                           x, identity, wr, br, we, be, wsu, out);
    }
}

// Round 3
// 375.025 us; speedup vs baseline: 1.0555x; 1.0211x over previous
//
#include <hip/hip_runtime.h>
#include <hip/hip_cooperative_groups.h>
#include <math.h>

namespace cg = cooperative_groups;

#define QMAX 127.0f
#define CIN 32
#define CR 8
#define HW 16384                 // 128*128
#define BATCH 64
#define NPIX (BATCH*HW)          // 1,048,576 pixels
#define NQUAD (NPIX/4)           // 262,144 pixel-quads
#define NX (BATCH*CIN*HW)        // 33,554,432 x elements
#define COOP_BLOCKS (NQUAD/256)  // 1024 blocks -> exactly 1 quad per thread

// ws layout: wsu[0]=amax_x bits, wsu[1]=amax_h bits; h buffer (fallback only) at wsf+64
#define H_OFF 64
#define WS_NEEDED ((size_t)(H_OFF + (size_t)NPIX * CR) * 4)

__device__ __forceinline__ float fq(float v, float inv_scale, float scale) {
    return rintf(fminf(fmaxf(v * inv_scale, -QMAX), QMAX)) * scale;  // round-half-even
}
__device__ __forceinline__ float sigmoidf_(float v) {
    return __builtin_amdgcn_rcpf(1.0f + __expf(-v));   // v_rcp_f32: ~1ulp, fine vs 5.5e-2 thr
}

// ================= Cooperative fused kernel =================
// grid = 1024 blocks x 256 thr; __launch_bounds__(256,4) caps VGPR<=128 -> 4 blocks/CU co-resident.
__global__ __launch_bounds__(256, 4) void se_fused(const float* __restrict__ x,
                                                   const float* __restrict__ identity,
                                                   const float* __restrict__ wr,
                                                   const float* __restrict__ br,
                                                   const float* __restrict__ we,
                                                   const float* __restrict__ be,
                                                   unsigned int* __restrict__ wsu,
                                                   float* __restrict__ out) {
    cg::grid_group grid = cg::this_grid();
    int t = threadIdx.x;
    __shared__ float wqr[CR * CIN], wqe[CIN * CR], bsh[CR], besh[CIN], amr[CR], ame[CIN];
    __shared__ float red[4];

    // ---- weight quantization (per-block, tiny) ----
    if (t < CR) {
        float mm = 0.f;
        for (int c = 0; c < CIN; c++) mm = fmaxf(mm, fabsf(wr[t * CIN + c]));
        amr[t] = fmaxf(mm, 1e-12f);
        bsh[t] = br[t];
    }
    if (t >= 64 && t < 64 + CIN) {
        int r = t - 64;
        float mm = 0.f;
        for (int c = 0; c < CR; c++) mm = fmaxf(mm, fabsf(we[r * CR + c]));
        ame[r] = fmaxf(mm, 1e-12f);
        besh[r] = be[r];
    }
    __syncthreads();
    {
        float a1 = amr[t >> 5];
        wqr[t] = fq(wr[t], QMAX / a1, a1 * (1.f / QMAX));
        float a2 = ame[t >> 3];
        wqe[t] = fq(we[t], QMAX / a2, a2 * (1.f / QMAX));
    }
    __syncthreads();

    const int tid = blockIdx.x * 256 + t;

    // ---- phase 1: global max|x| (32 float4 per thread, grid covers NX exactly) ----
    {
        const float4* x4 = (const float4*)x;
        float m = 0.f;
#pragma unroll 8
        for (int i = 0; i < 32; i++) {
            float4 v = x4[tid + i * NQUAD];
            m = fmaxf(m, fmaxf(fmaxf(fabsf(v.x), fabsf(v.y)), fmaxf(fabsf(v.z), fabsf(v.w))));
        }
#pragma unroll
        for (int off = 32; off > 0; off >>= 1) m = fmaxf(m, __shfl_xor(m, off, 64));
        if ((t & 63) == 0) red[t >> 6] = m;
        __syncthreads();
        if (t == 0) {
            m = fmaxf(fmaxf(red[0], red[1]), fmaxf(red[2], red[3]));
            atomicMax(&wsu[0], __float_as_uint(m));   // values >=0: uint order == float order
        }
    }
    grid.sync();

    // ---- phase 2: h = SiLU(conv_reduce(quant(x))) kept in registers; global max|h| ----
    float a_amax = fmaxf(__uint_as_float(
        __hip_atomic_load(&wsu[0], __ATOMIC_ACQUIRE, __HIP_MEMORY_SCOPE_AGENT)), 1e-12f);
    float ascale = a_amax * (1.f / QMAX), ainv = QMAX / a_amax;
    const int b = tid >> 12;
    const int hw = (tid & 4095) << 2;
    const size_t base = (size_t)b * CIN * HW + hw;
    float h[CR][4];
    {
        float hacc[CR][4];
#pragma unroll
        for (int o = 0; o < CR; o++)
#pragma unroll
            for (int v = 0; v < 4; v++) hacc[o][v] = 0.f;
        const float* xb = x + base;
#pragma unroll
        for (int c = 0; c < CIN; c++) {
            float4 xv = *(const float4*)(xb + (size_t)c * HW);
            float q0 = fq(xv.x, ainv, ascale), q1 = fq(xv.y, ainv, ascale);
            float q2 = fq(xv.z, ainv, ascale), q3 = fq(xv.w, ainv, ascale);
#pragma unroll
            for (int o = 0; o < CR; o++) {
                float w = wqr[o * CIN + c];
                hacc[o][0] += q0 * w; hacc[o][1] += q1 * w;
                hacc[o][2] += q2 * w; hacc[o][3] += q3 * w;
            }
        }
        float m = 0.f;
#pragma unroll
        for (int o = 0; o < CR; o++) {
            float bb = bsh[o];
#pragma unroll
            for (int v = 0; v < 4; v++) {
                float hv = hacc[o][v] + bb;
                hv = hv * sigmoidf_(hv);
                h[o][v] = hv;
                m = fmaxf(m, fabsf(hv));
            }
        }
#pragma unroll
        for (int off = 32; off > 0; off >>= 1) m = fmaxf(m, __shfl_xor(m, off, 64));
        __syncthreads();                  // red[] reuse
        if ((t & 63) == 0) red[t >> 6] = m;
        __syncthreads();
        if (t == 0) {
            m = fmaxf(fmaxf(red[0], red[1]), fmaxf(red[2], red[3]));
            atomicMax(&wsu[1], __float_as_uint(m));
        }
    }
    grid.sync();

    // ---- phase 3: quantize h in-register, expand conv, identity * sigmoid(g) ----
    float h_amax = fmaxf(__uint_as_float(
        __hip_atomic_load(&wsu[1], __ATOMIC_ACQUIRE, __HIP_MEMORY_SCOPE_AGENT)), 1e-12f);
    float hscale = h_amax * (1.f / QMAX), hinv = QMAX / h_amax;
#pragma unroll
    for (int o = 0; o < CR; o++)
#pragma unroll
        for (int v = 0; v < 4; v++) h[o][v] = fq(h[o][v], hinv, hscale);

#pragma unroll 4
    for (int o2 = 0; o2 < CIN; o2++) {
        float g0 = besh[o2], g1 = g0, g2 = g0, g3 = g0;
#pragma unroll
        for (int cr = 0; cr < CR; cr++) {
            float w = wqe[o2 * CR + cr];
            g0 += h[cr][0] * w; g1 += h[cr][1] * w;
            g2 += h[cr][2] * w; g3 += h[cr][3] * w;
        }
        size_t off = base + (size_t)o2 * HW;
        float4 idv = *(const float4*)(identity + off);
        float4 ov;
        ov.x = idv.x * sigmoidf_(g0);
        ov.y = idv.y * sigmoidf_(g1);
        ov.z = idv.z * sigmoidf_(g2);
        ov.w = idv.w * sigmoidf_(g3);
        *(float4*)(out + off) = ov;
    }
}

// ================= Fallback path (proven R2 kernels) =================
__global__ __launch_bounds__(256) void k1_xmax(const float4* __restrict__ x4,
                                               unsigned int* __restrict__ wsu) {
    int idx = blockIdx.x * 256 + threadIdx.x;
    float m = 0.f;
#pragma unroll
    for (int i = 0; i < 16; i++) {
        float4 v = x4[idx + i * 524288];
        m = fmaxf(m, fmaxf(fmaxf(fabsf(v.x), fabsf(v.y)), fmaxf(fabsf(v.z), fabsf(v.w))));
    }
#pragma unroll
    for (int off = 32; off > 0; off >>= 1) m = fmaxf(m, __shfl_xor(m, off, 64));
    __shared__ float red[4];
    int t = threadIdx.x;
    if ((t & 63) == 0) red[t >> 6] = m;
    __syncthreads();
    if (t == 0) {
        m = fmaxf(fmaxf(red[0], red[1]), fmaxf(red[2], red[3]));
        atomicMax(&wsu[0], __float_as_uint(m));
    }
}

__global__ __launch_bounds__(256) void k2_hmax(const float* __restrict__ x,
                                               const float* __restrict__ wr,
                                               const float* __restrict__ br,
                                               const unsigned int* __restrict__ wsu,
                                               unsigned int* __restrict__ hmax,
                                               float* __restrict__ hbuf) {
    __shared__ float wq[CR * CIN], bsh[CR], amr[CR];
    int t = threadIdx.x;
    if (t < CR) {
        float mm = 0.f;
        for (int c = 0; c < CIN; c++) mm = fmaxf(mm, fabsf(wr[t * CIN + c]));
        amr[t] = fmaxf(mm, 1e-12f);
        bsh[t] = br[t];
    }
    __syncthreads();
    {
        float amax = amr[t >> 5];
        wq[t] = fq(wr[t], QMAX / amax, amax * (1.f / QMAX));
    }
    __syncthreads();
    float a_amax = fmaxf(__uint_as_float(wsu[0]), 1e-12f);
    float scale = a_amax * (1.f / QMAX), inv_scale = QMAX / a_amax;
    int tid = blockIdx.x * 256 + t;
    int b = tid >> 12;
    int hw = (tid & 4095) << 2;
    const float* xb = x + (size_t)b * CIN * HW + hw;
    float hacc[CR][4];
#pragma unroll
    for (int o = 0; o < CR; o++)
#pragma unroll
        for (int v = 0; v < 4; v++) hacc[o][v] = 0.f;
#pragma unroll
    for (int c = 0; c < CIN; c++) {
        float4 xv = *(const float4*)(xb + (size_t)c * HW);
        float q0 = fq(xv.x, inv_scale, scale), q1 = fq(xv.y, inv_scale, scale);
        float q2 = fq(xv.z, inv_scale, scale), q3 = fq(xv.w, inv_scale, scale);
#pragma unroll
        for (int o = 0; o < CR; o++) {
            float w = wq[o * CIN + c];
            hacc[o][0] += q0 * w; hacc[o][1] += q1 * w;
            hacc[o][2] += q2 * w; hacc[o][3] += q3 * w;
        }
    }
    float m = 0.f;
#pragma unroll
    for (int o = 0; o < CR; o++) {
        float bb = bsh[o];
        float4 hv;
        float* hp = (float*)&hv;
#pragma unroll
        for (int v = 0; v < 4; v++) {
            float h = hacc[o][v] + bb;
            h = h * sigmoidf_(h);
            hp[v] = h;
            m = fmaxf(m, fabsf(h));
        }
        if (hbuf) *(float4*)(hbuf + ((size_t)(b * CR + o)) * HW + hw) = hv;
    }
#pragma unroll
    for (int off = 32; off > 0; off >>= 1) m = fmaxf(m, __shfl_xor(m, off, 64));
    __shared__ float red[4];
    if ((t & 63) == 0) red[t >> 6] = m;
    __syncthreads();
    if (t == 0) {
        m = fmaxf(fmaxf(red[0], red[1]), fmaxf(red[2], red[3]));
        atomicMax(hmax, __float_as_uint(m));
    }
}

__global__ __launch_bounds__(256) void k3_out(const float* __restrict__ hbuf,
                                              const float* __restrict__ identity,
                                              const float* __restrict__ we,
                                              const float* __restrict__ be,
                                              const unsigned int* __restrict__ wsu,
                                              float* __restrict__ out) {
    const int y = blockIdx.y;
    __shared__ float wqe[16 * CR], besh[16], ame[16];
    int t = threadIdx.x;
    if (t < 16) {
        int r = 16 * y + t;
        float mm = 0.f;
        for (int c = 0; c < CR; c++) mm = fmaxf(mm, fabsf(we[r * CR + c]));
        ame[t] = fmaxf(mm, 1e-12f);
        besh[t] = be[r];
    }
    __syncthreads();
    if (t < 128) {
        int r16 = t >> 3;
        float amax = ame[r16];
        wqe[t] = fq(we[(16 * y + r16) * CR + (t & 7)], QMAX / amax, amax * (1.f / QMAX));
    }
    __syncthreads();
    float h_amax = fmaxf(__uint_as_float(wsu[1]), 1e-12f);
    float hscale = h_amax * (1.f / QMAX), hinv = QMAX / h_amax;
    int tid = blockIdx.x * 256 + t;
    int b = tid >> 12;
    int hw = (tid & 4095) << 2;
    size_t base = (size_t)b * CIN * HW + hw;
    float hq[CR][4];
#pragma unroll
    for (int cr = 0; cr < CR; cr++) {
        float4 hv = *(const float4*)(hbuf + ((size_t)(b * CR + cr)) * HW + hw);
        hq[cr][0] = fq(hv.x, hinv, hscale);
        hq[cr][1] = fq(hv.y, hinv, hscale);
        hq[cr][2] = fq(hv.z, hinv, hscale);
        hq[cr][3] = fq(hv.w, hinv, hscale);
    }
#pragma unroll 4
    for (int o = 0; o < 16; o++) {
        float g0 = besh[o], g1 = g0, g2 = g0, g3 = g0;
#pragma unroll
        for (int cr = 0; cr < CR; cr++) {
            float w = wqe[o * CR + cr];
            g0 += hq[cr][0] * w; g1 += hq[cr][1] * w;
            g2 += hq[cr][2] * w; g3 += hq[cr][3] * w;
        }
        size_t off = base + (size_t)(16 * y + o) * HW;
        float4 idv = *(const float4*)(identity + off);
        float4 ov;
        ov.x = idv.x * sigmoidf_(g0);
        ov.y = idv.y * sigmoidf_(g1);
        ov.z = idv.z * sigmoidf_(g2);
        ov.w = idv.w * sigmoidf_(g3);
        *(float4*)(out + off) = ov;
    }
}

__global__ __launch_bounds__(256) void k3_out_rc(const float* __restrict__ x,
                                                 const float* __restrict__ identity,
                                                 const float* __restrict__ wr,
                                                 const float* __restrict__ br,
                                                 const float* __restrict__ we,
                                                 const float* __restrict__ be,
                                                 const unsigned int* __restrict__ wsu,
                                                 float* __restrict__ out) {
    __shared__ float wqr[CR * CIN], wqe[CIN * CR], bsh[CR], besh[CIN], amr[CR], ame[CIN];
    int t = threadIdx.x;
    if (t < CR) {
        float mm = 0.f;
        for (int c = 0; c < CIN; c++) mm = fmaxf(mm, fabsf(wr[t * CIN + c]));
        amr[t] = fmaxf(mm, 1e-12f);
        bsh[t] = br[t];
    }
    if (t >= 64 && t < 64 + CIN) {
        int r = t - 64;
        float mm = 0.f;
        for (int c = 0; c < CR; c++) mm = fmaxf(mm, fabsf(we[r * CR + c]));
        ame[r] = fmaxf(mm, 1e-12f);
        besh[r] = be[r];
    }
    __syncthreads();
    {
        float amax = amr[t >> 5];
        wqr[t] = fq(wr[t], QMAX / amax, amax * (1.f / QMAX));
        float amax2 = ame[t >> 3];
        wqe[t] = fq(we[t], QMAX / amax2, amax2 * (1.f / QMAX));
    }
    __syncthreads();
    float a_amax = fmaxf(__uint_as_float(wsu[0]), 1e-12f);
    float ascale = a_amax * (1.f / QMAX), ainv = QMAX / a_amax;
    float h_amax = fmaxf(__uint_as_float(wsu[1]), 1e-12f);
    float hscale = h_amax * (1.f / QMAX), hinv = QMAX / h_amax;
    int tid = blockIdx.x * 256 + t;
    int b = tid >> 12;
    int hw = (tid & 4095) << 2;
    size_t base = (size_t)b * CIN * HW + hw;
    const float* xb = x + base;
    float hq[CR][4];
    {
        float hacc[CR][4];
#pragma unroll
        for (int o = 0; o < CR; o++)
#pragma unroll
            for (int v = 0; v < 4; v++) hacc[o][v] = 0.f;
#pragma unroll
        for (int c = 0; c < CIN; c++) {
            float4 xv = *(const float4*)(xb + (size_t)c * HW);
            float q0 = fq(xv.x, ainv, ascale), q1 = fq(xv.y, ainv, ascale);
            float q2 = fq(xv.z, ainv, ascale), q3 = fq(xv.w, ainv, ascale);
#pragma unroll
            for (int o = 0; o < CR; o++) {
                float w = wqr[o * CIN + c];
                hacc[o][0] += q0 * w; hacc[o][1] += q1 * w;
                hacc[o][2] += q2 * w; hacc[o][3] += q3 * w;
            }
        }
#pragma unroll
        for (int o = 0; o < CR; o++) {
            float bb = bsh[o];
#pragma unroll
            for (int v = 0; v < 4; v++) {
                float h = hacc[o][v] + bb;
                h = h * sigmoidf_(h);
                hq[o][v] = fq(h, hinv, hscale);
            }
        }
    }
#pragma unroll 4
    for (int o2 = 0; o2 < CIN; o2++) {
        float g0 = besh[o2], g1 = g0, g2 = g0, g3 = g0;
#pragma unroll
        for (int cr = 0; cr < CR; cr++) {
            float w = wqe[o2 * CR + cr];
            g0 += hq[cr][0] * w; g1 += hq[cr][1] * w;
            g2 += hq[cr][2] * w; g3 += hq[cr][3] * w;
        }
        size_t off = base + (size_t)o2 * HW;
        float4 idv = *(const float4*)(identity + off);
        float4 ov;
        ov.x = idv.x * sigmoidf_(g0);
        ov.y = idv.y * sigmoidf_(g1);
        ov.z = idv.z * sigmoidf_(g2);
        ov.w = idv.w * sigmoidf_(g3);
        *(float4*)(out + off) = ov;
    }
}

extern "C" void kernel_launch(void* const* d_in, const int* in_sizes, int n_in,
                              void* d_out, int out_size, void* d_ws, size_t ws_size,
                              hipStream_t stream) {
    const float* x        = (const float*)d_in[0];
    const float* identity = (const float*)d_in[1];
    const float* wr       = (const float*)d_in[2];
    const float* br       = (const float*)d_in[3];
    const float* we       = (const float*)d_in[4];
    const float* be       = (const float*)d_in[5];
    float* out            = (float*)d_out;
    float* wsf            = (float*)d_ws;
    unsigned int* wsu     = (unsigned int*)d_ws;

    hipMemsetAsync(d_ws, 0, 16, stream);   // zero the two amax accumulators

    // Try the fused cooperative kernel (needs 4 blocks/CU co-residency).
    int maxb = 0;
    hipError_t qerr = hipOccupancyMaxActiveBlocksPerMultiprocessor(&maxb, se_fused, 256, 0);
    bool coop_ok = false;
    if (qerr == hipSuccess && maxb >= 4) {
        void* args[] = {(void*)&x, (void*)&identity, (void*)&wr, (void*)&br,
                        (void*)&we, (void*)&be, (void*)&wsu, (void*)&out};
        hipError_t lerr = hipLaunchCooperativeKernel((void*)se_fused, dim3(COOP_BLOCKS),
                                                     dim3(256), args, 0, stream);
        coop_ok = (lerr == hipSuccess);
    }
    if (coop_ok) return;

    // Fallback: proven 3-kernel path.
    const bool big_ws = (ws_size >= WS_NEEDED);
    float* hbuf = big_ws ? (wsf + H_OFF) : nullptr;
    hipLaunchKernelGGL(k1_xmax, dim3(2048), dim3(256), 0, stream, (const float4*)x, wsu);
    hipLaunchKernelGGL(k2_hmax, dim3(NQUAD / 256), dim3(256), 0, stream,
                       x, wr, br, wsu, &wsu[1], hbuf);
    if (big_ws) {
        hipLaunchKernelGGL(k3_out, dim3(NQUAD / 256, 2), dim3(256), 0, stream,
                           hbuf, identity, we, be, wsu, out);
    } else {
        hipLaunchKernelGGL(k3_out_rc, dim3(NQUAD / 256), dim3(256), 0, stream,
                           x, identity, wr, br, we, be, wsu, out);
    }
}